// Round 3
// baseline (181.474 us; speedup 1.0000x reference)
//
#include <hip/hip_runtime.h>
#include <math.h>

// Problem constants
#define Bb   2
#define Hh   64
#define Ww   160
#define DIMc 256
#define Nn   (Hh * Ww)                 // 10240 positions per batch
#define SCALEf 0.17677669529663687f    // 32^-0.5

typedef unsigned short u16;
typedef unsigned int   u32;
typedef __bf16 bf16x8 __attribute__((ext_vector_type(8)));
typedef float  f32x4  __attribute__((ext_vector_type(4)));

// fp32 -> bf16 round-to-nearest-even
__device__ __forceinline__ u16 f2bf(float f) {
    u32 u = __float_as_uint(f);
    u += 0x7fffu + ((u >> 16) & 1u);
    return (u16)(u >> 16);
}
__device__ __forceinline__ u32 pack2(float lo, float hi) {
    return (u32)f2bf(lo) | ((u32)f2bf(hi) << 16);
}
// packed bf16 pair -> floats (exact)
__device__ __forceinline__ float bflo(u32 u) { return __uint_as_float(u << 16); }
__device__ __forceinline__ float bfhi(u32 u) { return __uint_as_float(u & 0xffff0000u); }

// ---------------------------------------------------------------------------
// prep: convert x to bf16 (blocks 0..5119) and all 4 weights to transposed
// bf16 (blocks 5120..6143).
// ---------------------------------------------------------------------------
__global__ __launch_bounds__(256) void prep(const float* __restrict__ x,
                                            const float* __restrict__ Wq,
                                            const float* __restrict__ Wk,
                                            const float* __restrict__ Wv,
                                            const float* __restrict__ Wp,
                                            u16* __restrict__ xb,
                                            u16* __restrict__ WtAll)
{
    const int bid = blockIdx.x;
    if (bid < 5120) {
        size_t id = (size_t)bid * 256 + threadIdx.x;   // one float4 per thread
        float4 vv = *(const float4*)(x + id * 4);
        ushort4 ov = make_ushort4(f2bf(vv.x), f2bf(vv.y), f2bf(vv.z), f2bf(vv.w));
        *(ushort4*)(xb + id * 4) = ov;
    } else {
        int id = (bid - 5120) * 256 + threadIdx.x;     // 0 .. 262143
        int wsel = id >> 16;
        int rem  = id & 65535;
        int kk = rem >> 8, nn = rem & 255;
        const float* W = (wsel == 0) ? Wq : (wsel == 1) ? Wk : (wsel == 2) ? Wv : Wp;
        WtAll[(size_t)wsel * 65536 + nn * 256 + kk] = f2bf(W[kk * 256 + nn]);
    }
}

// ---------------------------------------------------------------------------
// bf16 MFMA GEMM: C[128 x 256] block tile = A[128 x 256] @ Bt^T
// 256 threads = 4 waves in 2(m) x 2(n); wave computes 64x128 via 4x8 grid of
// 16x16x32 MFMAs. BK=32. A-tile read ONCE per output matrix.
// ---------------------------------------------------------------------------
template <bool BF16OUT>
__device__ __forceinline__ void gemm_core256(const u16* __restrict__ Ag,
                                             const u16* __restrict__ Btg,
                                             u16* __restrict__ Cb,
                                             float* __restrict__ Cf,
                                             int m0)
{
    __shared__ u16 sA[128 * 32];
    __shared__ u16 sB[256 * 32];

    const int t    = threadIdx.x;
    const int lane = t & 63;
    const int wv   = t >> 6;
    const int wm   = wv & 1;       // m-half (64 rows)
    const int wn   = wv >> 1;      // n-half (128 cols)
    const int col  = lane & 15;
    const int quad = lane >> 4;

    f32x4 acc[4][8];
#pragma unroll
    for (int i = 0; i < 4; ++i)
#pragma unroll
        for (int j = 0; j < 8; ++j)
            acc[i][j] = (f32x4){0.f, 0.f, 0.f, 0.f};

    const u16* Abase = Ag + (size_t)m0 * 256;

    for (int k0 = 0; k0 < 256; k0 += 32) {
        uint4 av[2], bv[4];
#pragma unroll
        for (int i = 0; i < 2; ++i) {
            int c = i * 256 + t, r = c >> 2, kc = (c & 3) * 8;
            av[i] = *(const uint4*)(Abase + (size_t)r * 256 + k0 + kc);
        }
#pragma unroll
        for (int i = 0; i < 4; ++i) {
            int c = i * 256 + t, r = c >> 2, kc = (c & 3) * 8;
            bv[i] = *(const uint4*)(Btg + (size_t)r * 256 + k0 + kc);
        }
        __syncthreads();
#pragma unroll
        for (int i = 0; i < 2; ++i) {
            int c = i * 256 + t, r = c >> 2, kc = (c & 3) * 8;
            *(uint4*)(sA + r * 32 + kc) = av[i];
        }
#pragma unroll
        for (int i = 0; i < 4; ++i) {
            int c = i * 256 + t, r = c >> 2, kc = (c & 3) * 8;
            *(uint4*)(sB + r * 32 + kc) = bv[i];
        }
        __syncthreads();

        bf16x8 af[4], bfr[8];
#pragma unroll
        for (int mt = 0; mt < 4; ++mt)
            af[mt] = *(const bf16x8*)(sA + (wm * 64 + mt * 16 + col) * 32 + quad * 8);
#pragma unroll
        for (int nt = 0; nt < 8; ++nt)
            bfr[nt] = *(const bf16x8*)(sB + (wn * 128 + nt * 16 + col) * 32 + quad * 8);

#pragma unroll
        for (int mt = 0; mt < 4; ++mt)
#pragma unroll
            for (int nt = 0; nt < 8; ++nt)
                acc[mt][nt] = __builtin_amdgcn_mfma_f32_16x16x32_bf16(af[mt], bfr[nt], acc[mt][nt], 0, 0, 0);
    }

    // epilogue: C/D layout col=lane&15, row=quad*4+reg
#pragma unroll
    for (int mt = 0; mt < 4; ++mt) {
#pragma unroll
        for (int nt = 0; nt < 8; ++nt) {
            const int rowb = m0 + wm * 64 + mt * 16 + quad * 4;
            const int colg = wn * 128 + nt * 16 + col;
#pragma unroll
            for (int rr = 0; rr < 4; ++rr) {
                float val = acc[mt][nt][rr];
                if (BF16OUT) Cb[(size_t)(rowb + rr) * 256 + colg] = f2bf(val);
                else         Cf[(size_t)(rowb + rr) * 256 + colg] = val;
            }
        }
    }
}

__global__ __launch_bounds__(256, 2) void gemm_qkv(const u16* __restrict__ xb,
                                                   const u16* __restrict__ WtAll,
                                                   u16* __restrict__ q,
                                                   u16* __restrict__ k,
                                                   u16* __restrict__ v)
{
    const int z = blockIdx.y;
    u16* C = (z == 0) ? q : (z == 1) ? k : v;
    gemm_core256<true>(xb, WtAll + (size_t)z * 65536, C, nullptr, blockIdx.x * 128);
}

__global__ __launch_bounds__(256, 2) void gemm_proj(const u16* __restrict__ ao,
                                                    const u16* __restrict__ WtAll,
                                                    float* __restrict__ out)
{
    gemm_core256<false>(ao, WtAll + (size_t)3 * 65536, nullptr, out, blockIdx.x * 128);
}

// ---------------------------------------------------------------------------
// Attention: ONE WAVE per position. No LDS, no __syncthreads.
// Lane (a = L>>3, h = L&7): scores phase reads k rows in contiguous 512B
// bursts; softmax via shfl_xor butterfly over lanes sharing a head; P
// distributed via shfl; P.V with coalesced 512B row loads.
// ---------------------------------------------------------------------------
__global__ __launch_bounds__(256) void attn_kernel(const u16* __restrict__ q,
                                                   const u16* __restrict__ k,
                                                   const u16* __restrict__ v,
                                                   const float* __restrict__ moff,
                                                   u16* __restrict__ ao)
{
    const int wv   = threadIdx.x >> 6;
    const int lane = threadIdx.x & 63;
    const int pos  = blockIdx.x * 4 + wv;
    const int rowbase = (pos >= Nn) ? Nn : 0;

    // window geometry (all lanes, cheap)
    float2 mo = *(const float2*)(moff + (size_t)pos * 2);
    float ox = fminf(fmaxf(mo.x, 1.0f), (float)(Ww - 2) - 0.001f);
    float oy = fminf(fmaxf(mo.y, 1.0f), (float)(Hh - 2) - 0.001f);
    float mxf = floorf(ox), myf = floorf(oy);
    float fx = ox - mxf, fy = oy - myf;
    int imx = (int)mxf, imy = (int)myf;

    const int h  = lane & 7;
    const int a0 = lane >> 3;   // this lane's first window element

    // q slice for head h: 64B (8 lanes share the row -> L1 broadcast)
    uint4 q4[4];
    {
        const uint4* qp = (const uint4*)(q + (size_t)pos * 256 + h * 32);
#pragma unroll
        for (int jj = 0; jj < 4; ++jj) q4[jj] = qp[jj];
    }

    // scores for a0 and a0+8
    float s[2];
#pragma unroll
    for (int p = 0; p < 2; ++p) {
        int a   = a0 + 8 * p;
        int row = rowbase + (imy + (a >> 2) - 1) * Ww + imx + (a & 3) - 1;
        const uint4* kp = (const uint4*)(k + (size_t)row * 256 + h * 32);
        float acc = 0.f;
#pragma unroll
        for (int jj = 0; jj < 4; ++jj) {
            uint4 kw = kp[jj];
            acc += bflo(q4[jj].x) * bflo(kw.x) + bfhi(q4[jj].x) * bfhi(kw.x)
                 + bflo(q4[jj].y) * bflo(kw.y) + bfhi(q4[jj].y) * bfhi(kw.y)
                 + bflo(q4[jj].z) * bflo(kw.z) + bfhi(q4[jj].z) * bfhi(kw.z)
                 + bflo(q4[jj].w) * bflo(kw.w) + bfhi(q4[jj].w) * bfhi(kw.w);
        }
        s[p] = acc * SCALEf;
    }

    // bilinear weights for this lane's two window elems
    auto wc = [](int r, float f) { return r == 0 ? 1.f - f : (r == 3 ? f : 1.f); };
    float bw0 = wc(a0 >> 2, fy) * wc(a0 & 3, fx);          // a0 in 0..7  -> ry 0..1
    float bw1 = wc((a0 + 8) >> 2, fy) * wc(a0 & 3, fx);    // a0+8       -> ry 2..3

    // softmax across the 8 lanes sharing head h (lanes h, h+8, ..., h+56)
    float m = fmaxf(s[0], s[1]);
    m = fmaxf(m, __shfl_xor(m, 8));
    m = fmaxf(m, __shfl_xor(m, 16));
    m = fmaxf(m, __shfl_xor(m, 32));
    float e0 = expf(s[0] - m) * bw0;
    float e1 = expf(s[1] - m) * bw1;
    float sum = e0 + e1;
    sum += __shfl_xor(sum, 8);
    sum += __shfl_xor(sum, 16);
    sum += __shfl_xor(sum, 32);
    float inv = 1.f / sum;
    float p0 = e0 * inv, p1 = e1 * inv;

    // P.V: lane covers channels 4*lane..4*lane+3; its head = lane>>3.
    float acc0 = 0.f, acc1 = 0.f, acc2 = 0.f, acc3 = 0.f;
    const int myh = lane >> 3;
#pragma unroll
    for (int a = 0; a < 16; ++a) {
        int row = rowbase + (imy + (a >> 2) - 1) * Ww + imx + (a & 3) - 1;
        uint2 vw = *(const uint2*)(v + (size_t)row * 256 + 4 * lane);
        int src = ((a & 7) << 3) | myh;                 // lane holding p(a, myh)
        float pa = __shfl(a < 8 ? p0 : p1, src);
        acc0 += pa * bflo(vw.x); acc1 += pa * bfhi(vw.x);
        acc2 += pa * bflo(vw.y); acc3 += pa * bfhi(vw.y);
    }
    uint2 o;
    o.x = pack2(acc0, acc1);
    o.y = pack2(acc2, acc3);
    *(uint2*)(ao + (size_t)pos * 256 + 4 * lane) = o;
}

// ---------------------------------------------------------------------------
extern "C" void kernel_launch(void* const* d_in, const int* in_sizes, int n_in,
                              void* d_out, int out_size, void* d_ws, size_t ws_size,
                              hipStream_t stream)
{
    const float* x     = (const float*)d_in[0];
    const float* moff  = (const float*)d_in[1];
    const float* Wq    = (const float*)d_in[2];
    const float* Wk    = (const float*)d_in[3];
    const float* Wv    = (const float*)d_in[4];
    const float* Wproj = (const float*)d_in[5];
    float* out = (float*)d_out;

    const size_t NTOT = (size_t)Bb * Nn * DIMc;   // 5,242,880
    u16* ws    = (u16*)d_ws;
    u16* xb    = ws;
    u16* WtAll = xb + NTOT;
    u16* q     = WtAll + 4 * 65536;
    u16* k     = q + NTOT;
    u16* v     = k + NTOT;
    u16* ao    = v + NTOT;

    prep<<<dim3(6144), dim3(256), 0, stream>>>(x, Wq, Wk, Wv, Wproj, xb, WtAll);
    gemm_qkv<<<dim3(160, 3), dim3(256), 0, stream>>>(xb, WtAll, q, k, v);
    attn_kernel<<<dim3(Bb * Nn / 4), dim3(256), 0, stream>>>(q, k, v, moff, ao);
    gemm_proj<<<dim3(160), dim3(256), 0, stream>>>(ao, WtAll, out);
}

// Round 4
// 146.200 us; speedup vs baseline: 1.2413x; 1.2413x over previous
//
#include <hip/hip_runtime.h>
#include <math.h>

// Problem constants
#define Bb   2
#define Hh   64
#define Ww   160
#define DIMc 256
#define Nn   (Hh * Ww)                 // 10240 positions per batch
#define SCALEf 0.17677669529663687f    // 32^-0.5

typedef unsigned short u16;
typedef unsigned int   u32;
typedef __bf16 bf16x8 __attribute__((ext_vector_type(8)));
typedef float  f32x4  __attribute__((ext_vector_type(4)));

// fp32 -> bf16 round-to-nearest-even
__device__ __forceinline__ u16 f2bf(float f) {
    u32 u = __float_as_uint(f);
    u += 0x7fffu + ((u >> 16) & 1u);
    return (u16)(u >> 16);
}
__device__ __forceinline__ u32 pack2(float lo, float hi) {
    return (u32)f2bf(lo) | ((u32)f2bf(hi) << 16);
}
// packed bf16 pair -> floats (exact)
__device__ __forceinline__ float bflo(u32 u) { return __uint_as_float(u << 16); }
__device__ __forceinline__ float bfhi(u32 u) { return __uint_as_float(u & 0xffff0000u); }

// ---------------------------------------------------------------------------
// prep: convert x to bf16 (blocks 0..5119) and all 4 weights to transposed
// bf16 (blocks 5120..6143).
// ---------------------------------------------------------------------------
__global__ __launch_bounds__(256) void prep(const float* __restrict__ x,
                                            const float* __restrict__ Wq,
                                            const float* __restrict__ Wk,
                                            const float* __restrict__ Wv,
                                            const float* __restrict__ Wp,
                                            u16* __restrict__ xb,
                                            u16* __restrict__ WtAll)
{
    const int bid = blockIdx.x;
    if (bid < 5120) {
        size_t id = (size_t)bid * 256 + threadIdx.x;   // one float4 per thread
        float4 vv = *(const float4*)(x + id * 4);
        ushort4 ov = make_ushort4(f2bf(vv.x), f2bf(vv.y), f2bf(vv.z), f2bf(vv.w));
        *(ushort4*)(xb + id * 4) = ov;
    } else {
        int id = (bid - 5120) * 256 + threadIdx.x;     // 0 .. 262143
        int wsel = id >> 16;
        int rem  = id & 65535;
        int kk = rem >> 8, nn = rem & 255;
        const float* W = (wsel == 0) ? Wq : (wsel == 1) ? Wk : (wsel == 2) ? Wv : Wp;
        WtAll[(size_t)wsel * 65536 + nn * 256 + kk] = f2bf(W[kk * 256 + nn]);
    }
}

// ---------------------------------------------------------------------------
// bf16 MFMA GEMM: C[M x 256] = A[M x 256] @ Bt^T   (Bt is N-major 256x256)
// 128x128 block tile, 256 threads = 4 waves in 2x2, each wave 4x4 grid of
// 16x16x32 MFMAs. BK=32. (R2-proven, no spills: acc = 64 VGPR/lane.)
// ---------------------------------------------------------------------------
template <bool BF16OUT>
__device__ __forceinline__ void gemm_core(const u16* __restrict__ Ag,
                                          const u16* __restrict__ Btg,
                                          u16* __restrict__ Cb,
                                          float* __restrict__ Cf)
{
    __shared__ u16 sA[128 * 32];
    __shared__ u16 sB[128 * 32];

    const int t    = threadIdx.x;
    const int lane = t & 63;
    const int wv   = t >> 6;
    const int wm   = wv & 1;      // wave m-half
    const int wn   = wv >> 1;     // wave n-half
    const int m0   = blockIdx.y * 128;
    const int n0   = blockIdx.x * 128;

    // staging: thread t covers rows r0 and r0+64, 8 bf16 (16B) each
    const int r0  = t >> 2;
    const int kc0 = (t & 3) * 8;

    const int col  = lane & 15;
    const int quad = lane >> 4;

    f32x4 acc[4][4];
#pragma unroll
    for (int i = 0; i < 4; ++i)
#pragma unroll
        for (int j = 0; j < 4; ++j)
            acc[i][j] = (f32x4){0.f, 0.f, 0.f, 0.f};

    const u16* Abase = Ag + (size_t)m0 * 256;
    const u16* Bbase = Btg + (size_t)n0 * 256;

    for (int k0 = 0; k0 < 256; k0 += 32) {
        uint4 a0 = *(const uint4*)(Abase + (size_t)r0 * 256 + k0 + kc0);
        uint4 a1 = *(const uint4*)(Abase + (size_t)(64 + r0) * 256 + k0 + kc0);
        uint4 b0 = *(const uint4*)(Bbase + (size_t)r0 * 256 + k0 + kc0);
        uint4 b1 = *(const uint4*)(Bbase + (size_t)(64 + r0) * 256 + k0 + kc0);
        __syncthreads();
        *(uint4*)(sA + r0 * 32 + kc0)        = a0;
        *(uint4*)(sA + (64 + r0) * 32 + kc0) = a1;
        *(uint4*)(sB + r0 * 32 + kc0)        = b0;
        *(uint4*)(sB + (64 + r0) * 32 + kc0) = b1;
        __syncthreads();

        bf16x8 af[4], bfr[4];
#pragma unroll
        for (int mt = 0; mt < 4; ++mt)
            af[mt] = *(const bf16x8*)(sA + (wm * 64 + mt * 16 + col) * 32 + quad * 8);
#pragma unroll
        for (int nt = 0; nt < 4; ++nt)
            bfr[nt] = *(const bf16x8*)(sB + (wn * 64 + nt * 16 + col) * 32 + quad * 8);

#pragma unroll
        for (int mt = 0; mt < 4; ++mt)
#pragma unroll
            for (int nt = 0; nt < 4; ++nt)
                acc[mt][nt] = __builtin_amdgcn_mfma_f32_16x16x32_bf16(af[mt], bfr[nt], acc[mt][nt], 0, 0, 0);
    }

    // epilogue: C/D layout col=lane&15, row=quad*4+reg  (m89-verified)
#pragma unroll
    for (int mt = 0; mt < 4; ++mt) {
#pragma unroll
        for (int nt = 0; nt < 4; ++nt) {
            const int rowb = m0 + wm * 64 + mt * 16 + quad * 4;
            const int colg = n0 + wn * 64 + nt * 16 + col;
#pragma unroll
            for (int rr = 0; rr < 4; ++rr) {
                float val = acc[mt][nt][rr];
                if (BF16OUT) Cb[(size_t)(rowb + rr) * 256 + colg] = f2bf(val);
                else         Cf[(size_t)(rowb + rr) * 256 + colg] = val;
            }
        }
    }
}

__global__ __launch_bounds__(256) void gemm_qkv(const u16* __restrict__ xb,
                                                const u16* __restrict__ WtAll,
                                                u16* __restrict__ q,
                                                u16* __restrict__ k,
                                                u16* __restrict__ v)
{
    const int z = blockIdx.z;
    u16* C = (z == 0) ? q : (z == 1) ? k : v;
    gemm_core<true>(xb, WtAll + (size_t)z * 65536, C, nullptr);
}

__global__ __launch_bounds__(256) void gemm_proj(const u16* __restrict__ ao,
                                                 const u16* __restrict__ WtAll,
                                                 float* __restrict__ out)
{
    gemm_core<false>(ao, WtAll + (size_t)3 * 65536, nullptr, out);
}

// ---------------------------------------------------------------------------
// Attention: ONE WAVE per position. No LDS, no __syncthreads.
// Lane (a = L>>3, h = L&7): scores phase reads k rows in contiguous 512B
// bursts; softmax via shfl_xor butterfly over lanes sharing a head; P
// distributed via shfl; P.V with coalesced 512B row loads.
// ---------------------------------------------------------------------------
__global__ __launch_bounds__(256) void attn_kernel(const u16* __restrict__ q,
                                                   const u16* __restrict__ k,
                                                   const u16* __restrict__ v,
                                                   const float* __restrict__ moff,
                                                   u16* __restrict__ ao)
{
    const int wv   = threadIdx.x >> 6;
    const int lane = threadIdx.x & 63;
    const int pos  = blockIdx.x * 4 + wv;
    const int rowbase = (pos >= Nn) ? Nn : 0;

    // window geometry (all lanes, cheap)
    float2 mo = *(const float2*)(moff + (size_t)pos * 2);
    float ox = fminf(fmaxf(mo.x, 1.0f), (float)(Ww - 2) - 0.001f);
    float oy = fminf(fmaxf(mo.y, 1.0f), (float)(Hh - 2) - 0.001f);
    float mxf = floorf(ox), myf = floorf(oy);
    float fx = ox - mxf, fy = oy - myf;
    int imx = (int)mxf, imy = (int)myf;

    const int h  = lane & 7;
    const int a0 = lane >> 3;   // this lane's first window element

    // q slice for head h: 64B (8 lanes share the row -> L1 broadcast)
    uint4 q4[4];
    {
        const uint4* qp = (const uint4*)(q + (size_t)pos * 256 + h * 32);
#pragma unroll
        for (int jj = 0; jj < 4; ++jj) q4[jj] = qp[jj];
    }

    // scores for a0 and a0+8
    float s[2];
#pragma unroll
    for (int p = 0; p < 2; ++p) {
        int a   = a0 + 8 * p;
        int row = rowbase + (imy + (a >> 2) - 1) * Ww + imx + (a & 3) - 1;
        const uint4* kp = (const uint4*)(k + (size_t)row * 256 + h * 32);
        float acc = 0.f;
#pragma unroll
        for (int jj = 0; jj < 4; ++jj) {
            uint4 kw = kp[jj];
            acc += bflo(q4[jj].x) * bflo(kw.x) + bfhi(q4[jj].x) * bfhi(kw.x)
                 + bflo(q4[jj].y) * bflo(kw.y) + bfhi(q4[jj].y) * bfhi(kw.y)
                 + bflo(q4[jj].z) * bflo(kw.z) + bfhi(q4[jj].z) * bfhi(kw.z)
                 + bflo(q4[jj].w) * bflo(kw.w) + bfhi(q4[jj].w) * bfhi(kw.w);
        }
        s[p] = acc * SCALEf;
    }

    // bilinear weights for this lane's two window elems
    auto wc = [](int r, float f) { return r == 0 ? 1.f - f : (r == 3 ? f : 1.f); };
    float bw0 = wc(a0 >> 2, fy) * wc(a0 & 3, fx);          // a0 in 0..7  -> ry 0..1
    float bw1 = wc((a0 + 8) >> 2, fy) * wc(a0 & 3, fx);    // a0+8       -> ry 2..3

    // softmax across the 8 lanes sharing head h (lanes h, h+8, ..., h+56)
    float m = fmaxf(s[0], s[1]);
    m = fmaxf(m, __shfl_xor(m, 8));
    m = fmaxf(m, __shfl_xor(m, 16));
    m = fmaxf(m, __shfl_xor(m, 32));
    float e0 = expf(s[0] - m) * bw0;
    float e1 = expf(s[1] - m) * bw1;
    float sum = e0 + e1;
    sum += __shfl_xor(sum, 8);
    sum += __shfl_xor(sum, 16);
    sum += __shfl_xor(sum, 32);
    float inv = 1.f / sum;
    float p0 = e0 * inv, p1 = e1 * inv;

    // P.V: lane covers channels 4*lane..4*lane+3; its head = lane>>3.
    float acc0 = 0.f, acc1 = 0.f, acc2 = 0.f, acc3 = 0.f;
    const int myh = lane >> 3;
#pragma unroll
    for (int a = 0; a < 16; ++a) {
        int row = rowbase + (imy + (a >> 2) - 1) * Ww + imx + (a & 3) - 1;
        uint2 vw = *(const uint2*)(v + (size_t)row * 256 + 4 * lane);
        int src = ((a & 7) << 3) | myh;                 // lane holding p(a, myh)
        float pa = __shfl(a < 8 ? p0 : p1, src);
        acc0 += pa * bflo(vw.x); acc1 += pa * bfhi(vw.x);
        acc2 += pa * bflo(vw.y); acc3 += pa * bfhi(vw.y);
    }
    uint2 o;
    o.x = pack2(acc0, acc1);
    o.y = pack2(acc2, acc3);
    *(uint2*)(ao + (size_t)pos * 256 + 4 * lane) = o;
}

// ---------------------------------------------------------------------------
extern "C" void kernel_launch(void* const* d_in, const int* in_sizes, int n_in,
                              void* d_out, int out_size, void* d_ws, size_t ws_size,
                              hipStream_t stream)
{
    const float* x     = (const float*)d_in[0];
    const float* moff  = (const float*)d_in[1];
    const float* Wq    = (const float*)d_in[2];
    const float* Wk    = (const float*)d_in[3];
    const float* Wv    = (const float*)d_in[4];
    const float* Wproj = (const float*)d_in[5];
    float* out = (float*)d_out;

    const size_t NTOT = (size_t)Bb * Nn * DIMc;   // 5,242,880
    u16* ws    = (u16*)d_ws;
    u16* xb    = ws;
    u16* WtAll = xb + NTOT;
    u16* q     = WtAll + 4 * 65536;
    u16* k     = q + NTOT;
    u16* v     = k + NTOT;
    u16* ao    = v + NTOT;

    prep<<<dim3(6144), dim3(256), 0, stream>>>(x, Wq, Wk, Wv, Wproj, xb, WtAll);
    gemm_qkv<<<dim3(2, 160, 3), dim3(256), 0, stream>>>(xb, WtAll, q, k, v);
    attn_kernel<<<dim3(Bb * Nn / 4), dim3(256), 0, stream>>>(q, k, v, moff, ao);
    gemm_proj<<<dim3(2, 160, 1), dim3(256), 0, stream>>>(ao, WtAll, out);
}